// Round 1
// baseline (194.717 us; speedup 1.0000x reference)
//
#include <hip/hip_runtime.h>
#include <hip/hip_bf16.h>

#define N_NODES 200000
#define KDIM 27
#define C_IN 32
#define C_OUT 32

typedef __bf16 bf16x8 __attribute__((ext_vector_type(8)));
typedef float floatx4 __attribute__((ext_vector_type(4)));
typedef float float4_t __attribute__((ext_vector_type(4)));

__device__ inline bf16x8 zero_bf16x8() {
    bf16x8 z;
#pragma unroll
    for (int i = 0; i < 8; ++i) z[i] = (__bf16)0.0f;
    return z;
}

// Kernel 1: convert fp32 data -> bf16 (8 elems/thread, float4 in, 16B out)
__global__ __launch_bounds__(256) void convert_data_kernel(
    const float* __restrict__ src, __bf16* __restrict__ dst) {
    int i = blockIdx.x * 256 + threadIdx.x;   // 800000 threads, exact
    const float4_t* s = (const float4_t*)src;
    float4_t v0 = s[2 * i];
    float4_t v1 = s[2 * i + 1];
    bf16x8 o;
    o[0] = (__bf16)v0[0]; o[1] = (__bf16)v0[1];
    o[2] = (__bf16)v0[2]; o[3] = (__bf16)v0[3];
    o[4] = (__bf16)v1[0]; o[5] = (__bf16)v1[1];
    o[6] = (__bf16)v1[2]; o[7] = (__bf16)v1[3];
    ((bf16x8*)dst)[i] = o;
}

// Kernel 2: pack weights [K][C_IN][C_OUT] fp32 -> bf16 B-fragment layout:
// wp[((kk*2 + t)*64 + lane)*8 + j] = w[kk][ (lane>>4)*8 + j ][ t*16 + (lane&15) ]
__global__ __launch_bounds__(256) void pack_weights_kernel(
    const float* __restrict__ w, __bf16* __restrict__ wp) {
    int id = blockIdx.x * 256 + threadIdx.x;   // 27648 threads, exact (108 blocks)
    int j = id & 7;
    int l = (id >> 3) & 63;
    int t = (id >> 9) & 1;
    int kk = id >> 10;
    int c = ((l >> 4) << 3) + j;
    int o = t * 16 + (l & 15);
    wp[id] = (__bf16)w[(kk * C_IN + c) * C_OUT + o];
}

// Kernel 3: main gather-GEMM. One wave handles 32 nodes x 32 outputs.
// A-fragment (16x16x32 bf16): A[m = lane&15][k = (lane>>4)*8 + j]
// C/D: col = lane&15, row = (lane>>4)*4 + reg
__global__ __launch_bounds__(256) void octconv_main_kernel(
    const int* __restrict__ neigh, const __bf16* __restrict__ data_bf,
    const __bf16* __restrict__ wpack, float* __restrict__ out) {
    int tid  = threadIdx.x;
    int wave = tid >> 6;
    int lane = tid & 63;
    int node_base = (blockIdx.x * 4 + wave) * 32;
    int r16  = lane & 15;
    int half = lane >> 4;
    int cb   = half << 3;          // channel base for A fragment
    int m0   = node_base + r16;
    int m1   = m0 + 16;

    floatx4 acc00 = {0.f, 0.f, 0.f, 0.f};
    floatx4 acc01 = {0.f, 0.f, 0.f, 0.f};
    floatx4 acc10 = {0.f, 0.f, 0.f, 0.f};
    floatx4 acc11 = {0.f, 0.f, 0.f, 0.f};

    const bf16x8* wp = (const bf16x8*)wpack;   // [(kk*2 + t)*64 + lane]

#pragma unroll 3
    for (int kk = 0; kk < KDIM; ++kk) {
        int idx0 = (m0 < N_NODES) ? neigh[m0 * KDIM + kk] : -1;
        int idx1 = (m1 < N_NODES) ? neigh[m1 * KDIM + kk] : -1;

        bf16x8 a0 = zero_bf16x8();
        bf16x8 a1 = zero_bf16x8();
        if (idx0 >= 0) a0 = *(const bf16x8*)(data_bf + ((size_t)idx0 << 5) + cb);
        if (idx1 >= 0) a1 = *(const bf16x8*)(data_bf + ((size_t)idx1 << 5) + cb);

        bf16x8 b0 = wp[(kk * 2 + 0) * 64 + lane];
        bf16x8 b1 = wp[(kk * 2 + 1) * 64 + lane];

        acc00 = __builtin_amdgcn_mfma_f32_16x16x32_bf16(a0, b0, acc00, 0, 0, 0);
        acc01 = __builtin_amdgcn_mfma_f32_16x16x32_bf16(a0, b1, acc01, 0, 0, 0);
        acc10 = __builtin_amdgcn_mfma_f32_16x16x32_bf16(a1, b0, acc10, 0, 0, 0);
        acc11 = __builtin_amdgcn_mfma_f32_16x16x32_bf16(a1, b1, acc11, 0, 0, 0);
    }

#pragma unroll
    for (int r = 0; r < 4; ++r) {
        int row = half * 4 + r;
        int n0 = node_base + row;
        int n1 = n0 + 16;
        if (n0 < N_NODES) {
            out[n0 * C_OUT + r16]      = acc00[r];
            out[n0 * C_OUT + 16 + r16] = acc01[r];
        }
        if (n1 < N_NODES) {
            out[n1 * C_OUT + r16]      = acc10[r];
            out[n1 * C_OUT + 16 + r16] = acc11[r];
        }
    }
}

extern "C" void kernel_launch(void* const* d_in, const int* in_sizes, int n_in,
                              void* d_out, int out_size, void* d_ws, size_t ws_size,
                              hipStream_t stream) {
    const float* data    = (const float*)d_in[0];   // [N, C_IN] fp32
    const float* weights = (const float*)d_in[1];   // [K, C_IN, C_OUT] fp32
    const int*   neigh   = (const int*)d_in[2];     // [N, K] int32
    float*       out     = (float*)d_out;           // [N, C_OUT] fp32

    __bf16* data_bf = (__bf16*)d_ws;                               // 12.8 MB
    __bf16* wpack   = (__bf16*)((char*)d_ws + (size_t)N_NODES * C_IN * 2);  // 55 KB

    // 1) data fp32 -> bf16
    hipLaunchKernelGGL(convert_data_kernel, dim3((N_NODES * C_IN / 8 + 255) / 256),
                       dim3(256), 0, stream, data, data_bf);
    // 2) weights fp32 -> bf16 B-fragment pack
    hipLaunchKernelGGL(pack_weights_kernel, dim3((KDIM * C_IN * C_OUT + 255) / 256),
                       dim3(256), 0, stream, weights, wpack);
    // 3) gather + MFMA GEMM; 128 nodes per block
    int blocks = (N_NODES + 127) / 128;
    hipLaunchKernelGGL(octconv_main_kernel, dim3(blocks), dim3(256), 0, stream,
                       neigh, data_bf, wpack, out);
}